// Round 9
// baseline (663.228 us; speedup 1.0000x reference)
//
#include <hip/hip_runtime.h>

typedef unsigned short u16;
typedef __attribute__((ext_vector_type(8))) short short8;
typedef __attribute__((ext_vector_type(4))) float f32x4;

#define B_ 4
#define S_ 8192
#define D_ 1024
#define H_ 4096
#define NTOK (B_*S_)
#define MPAD 16384
#define KSEL 4096

// ---------- helpers ----------
__device__ __forceinline__ u16 f2b(float f) {  // fp32 -> bf16 RNE
    unsigned u = __float_as_uint(f);
    unsigned r = (u + 0x7FFFu + ((u >> 16) & 1u)) >> 16;
    return (u16)r;
}

__device__ __forceinline__ void async_load16(const void* g, void* l) {
    __builtin_amdgcn_global_load_lds(
        (const __attribute__((address_space(1))) void*)g,
        (__attribute__((address_space(3))) void*)l, 16, 0, 0);
}

// ---------- init ----------
__global__ void init_kernel(int* __restrict__ idx, int* __restrict__ cnt) {
    int t = blockIdx.x * 256 + threadIdx.x;
    if (t < MPAD) idx[t] = 0;
    if (t == 0) *cnt = 0;
}

// ---------- router ----------
__global__ __launch_bounds__(256)
void router_kernel(const float* __restrict__ x, const float* __restrict__ w_r,
                   const float* __restrict__ b_r, float* __restrict__ out,
                   u16* __restrict__ xb, float* __restrict__ wts) {
    int wv = threadIdx.x >> 6, lane = threadIdx.x & 63;
    long t = (long)blockIdx.x * 4 + wv;
    const float4* xrow = (const float4*)x + t * 256;
    const float4* wr4  = (const float4*)w_r;
    float4* orow = (float4*)out + t * 256;
    double acc = 0.0;
#pragma unroll
    for (int j = 0; j < 4; ++j) {
        int e = lane + j * 64;
        float4 v = xrow[e];
        float4 w = wr4[e];
        acc += (double)v.x * w.x + (double)v.y * w.y +
               (double)v.z * w.z + (double)v.w * w.w;
        orow[e] = v;
        uint2 hv;
        hv.x = (unsigned)f2b(v.x) | ((unsigned)f2b(v.y) << 16);
        hv.y = (unsigned)f2b(v.z) | ((unsigned)f2b(v.w) << 16);
        *(uint2*)&xb[t * D_ + e * 4] = hv;
    }
#pragma unroll
    for (int off = 32; off > 0; off >>= 1) acc += __shfl_down(acc, off);
    if (lane == 0) wts[t] = (float)(acc + (double)b_r[0]);
}

// ---------- exact k-th largest per batch: 32-step bisection, no atomics ----------
__global__ __launch_bounds__(256)
void select_kernel(const float* __restrict__ w, float* __restrict__ thr) {
    int b = blockIdx.x;
    const float* wb = w + b * S_;
    int tid = threadIdx.x;
    unsigned uv[32];
#pragma unroll
    for (int j = 0; j < 32; ++j) {
        unsigned u = __float_as_uint(wb[tid + j * 256]);
        uv[j] = (u & 0x80000000u) ? ~u : (u | 0x80000000u);
    }
    __shared__ int partial[4];
    unsigned res = 0u;
    for (int bit = 31; bit >= 0; --bit) {
        unsigned cand = res | (1u << bit);
        int c = 0;
#pragma unroll
        for (int j = 0; j < 32; ++j) c += (uv[j] > cand) ? 1 : 0;
#pragma unroll
        for (int off = 32; off > 0; off >>= 1) c += __shfl_down(c, off);
        if ((tid & 63) == 0) partial[tid >> 6] = c;
        __syncthreads();
        int tot = partial[0] + partial[1] + partial[2] + partial[3];
        if (tot >= KSEL) res = cand;
        __syncthreads();
    }
    if (tid == 0) {
        unsigned vu = res + 1u;
        unsigned orig = (vu & 0x80000000u) ? (vu ^ 0x80000000u) : ~vu;
        thr[b] = __uint_as_float(orig);
    }
}

// ---------- compact ----------
__global__ void compact_kernel(const float* __restrict__ w, const float* __restrict__ thr,
                               int* __restrict__ idx, int* __restrict__ cnt) {
    int t = blockIdx.x * 256 + threadIdx.x;
    int b = t >> 13;
    if (w[t] > thr[b]) {
        int p = atomicAdd(cnt, 1);
        idx[p] = t;
    }
}

// ---------- transpose + cast ----------
__global__ void transpose_kernel(const float* __restrict__ W, u16* __restrict__ Wt,
                                 int R, int C) {
    __shared__ float tile[32][33];
    int c0 = blockIdx.x * 32, r0 = blockIdx.y * 32;
    int tx = threadIdx.x & 31, ty = threadIdx.x >> 5;
#pragma unroll
    for (int i = 0; i < 32; i += 8)
        tile[ty + i][tx] = W[(long)(r0 + ty + i) * C + c0 + tx];
    __syncthreads();
#pragma unroll
    for (int i = 0; i < 32; i += 8)
        Wt[(long)(c0 + ty + i) * R + r0 + tx] = f2b(tile[tx][ty + i]);
}

// ================= 256x256 8-phase GEMM (T1..T5, m201-faithful) =================
// asm ds_read_b128 (waitcnt-pass-invisible) issued BEFORE the barrier, manual
// lgkmcnt(0) AFTER it + one rule-#18 sched_barrier; counted vmcnt(4); setprio.
#define DSR(dst, off) asm volatile("ds_read_b128 %0, %1" : "=v"(dst) : "v"(off))

template<int NT, int NTILES, int MODE>
__global__ __launch_bounds__(512, 2)
void gemm8p(const u16* __restrict__ A, const u16* __restrict__ Bm,
            const float* __restrict__ bias, const int* __restrict__ idx,
            const int* __restrict__ cnt, void* __restrict__ outp) {
    extern __shared__ char smem[];
    constexpr int NI = NT / 2;
    constexpr long RB = (long)NT * 128;     // row bytes of A / B panels
    constexpr int LOG_NT = (NTILES == 16) ? 4 : 2;
    const int tid = threadIdx.x;
    const int lane = tid & 63;
    const int wv = tid >> 6, wm = wv >> 2, wn = wv & 3;
    const int fr = lane & 15, fq = lane >> 4;

    // T1: bijective XCD-chunked swizzle (NWG % 8 == 0)
    constexpr int NWG = NTILES * 64;
    constexpr int QX = NWG / 8;
    const int wg = blockIdx.x + blockIdx.y * NTILES;
    const int swz = (wg & 7) * QX + (wg >> 3);
    const int ntile = swz & (NTILES - 1);
    const int mtile = swz >> LOG_NT;

    // ---- staging: pre-swizzled global sources, linear LDS dest ----
    const int rl_s = tid >> 3;
    const unsigned colb = (unsigned)(((tid & 7) * 16) ^ ((rl_s & 7) << 4));
    const char* srcA[4]; const char* srcB[4];
#pragma unroll
    for (int h = 0; h < 2; ++h)
#pragma unroll
        for (int l = 0; l < 2; ++l) {
            int rl = h * 128 + l * 64 + rl_s;
            long arow = (MODE == 0) ? (long)idx[mtile * 256 + rl]
                                    : (long)(mtile * 256 + rl);
            srcA[h * 2 + l] = (const char*)A + arow * RB + colb;
            srcB[h * 2 + l] = (const char*)Bm + (long)(ntile * 256 + rl) * RB + colb;
        }
    const unsigned dstOff = (unsigned)((tid >> 3) * 128 + (tid & 7) * 16);

    // ---- LDS read bases (swizzled) ----
    const unsigned ldsbase = (unsigned)(unsigned long long)(void*)smem;
    unsigned ck[2];
    ck[0] = (unsigned)((fq * 16) ^ ((fr & 7) << 4));
    ck[1] = ck[0] ^ 64u;
    const unsigned ldsA = ldsbase + (unsigned)((wm * 128 + fr) * 128);
    const unsigned ldsB = ldsbase + 65536u + (unsigned)((wn * 64 + fr) * 128);

#define STAGE_A(t, h, db) { \
    async_load16(srcA[(h)*2+0] + (long)(t)*128, smem + (db)*32768 + (h)*16384 + dstOff); \
    async_load16(srcA[(h)*2+1] + (long)(t)*128, smem + (db)*32768 + (h)*16384 + 8192 + dstOff); }
#define STAGE_B(t, h, db) { \
    async_load16(srcB[(h)*2+0] + (long)(t)*128, smem + 65536 + (db)*32768 + (h)*16384 + dstOff); \
    async_load16(srcB[(h)*2+1] + (long)(t)*128, smem + 65536 + (db)*32768 + (h)*16384 + 8192 + dstOff); }
#define BAR() __builtin_amdgcn_s_barrier()
#define VM4() asm volatile("s_waitcnt vmcnt(4)" ::: "memory")

    f32x4 acc[8][4] = {};
    short8 bfr[2][4];

    // prologue: A(0),B(0) -> db0; B(1) -> db1 (stays in flight)
    STAGE_A(0, 0, 0); STAGE_A(0, 1, 0);
    STAGE_B(0, 0, 0); STAGE_B(0, 1, 0);
    STAGE_B(1, 0, 1); STAGE_B(1, 1, 1);
    asm volatile("s_waitcnt vmcnt(4)" ::: "memory");
    BAR();

    // phase: {asm reads in flight || stage} -> BAR -> lgkmcnt(0) -> fence ->
    //        prio1 16xMFMA prio0  (reads cross the barrier; m201 pattern)
#define PHASE(DB, KK, SLAB, BLOAD, STAGE_STMT) { \
    const unsigned rdb = (DB) * 32768u; \
    if (BLOAD) { \
        _Pragma("unroll") \
        for (int n = 0; n < 4; ++n) \
            DSR(bfr[KK][n], ldsB + rdb + (unsigned)(n) * 2048u + ck[KK]); \
    } \
    short8 afr[4]; \
    _Pragma("unroll") \
    for (int r = 0; r < 4; ++r) \
        DSR(afr[r], ldsA + rdb + (unsigned)((SLAB) + r) * 2048u + ck[KK]); \
    STAGE_STMT; \
    BAR(); \
    asm volatile("s_waitcnt lgkmcnt(0)" ::: "memory"); \
    __builtin_amdgcn_sched_barrier(0); \
    __builtin_amdgcn_s_setprio(1); \
    _Pragma("unroll") \
    for (int r = 0; r < 4; ++r) \
        _Pragma("unroll") \
        for (int n = 0; n < 4; ++n) \
            acc[(SLAB) + r][n] = __builtin_amdgcn_mfma_f32_16x16x32_bf16( \
                afr[r], bfr[KK][n], acc[(SLAB) + r][n], 0, 0, 0); \
    __builtin_amdgcn_s_setprio(0); }

    for (int i = 0; i < NI; ++i) {
        const int t0 = 2 * i;
        const int tA1 = t0 + 1;
        const int tB2 = (t0 + 2 >= NT) ? t0     : t0 + 2;   // parity-preserving clamp
        const int tB3 = (t0 + 3 >= NT) ? t0 + 1 : t0 + 3;
        PHASE(0, 0, 0, true,  STAGE_A(tA1, 0, 1)); BAR();
        PHASE(0, 1, 0, true,  STAGE_A(tA1, 1, 1)); BAR();
        PHASE(0, 0, 4, false, STAGE_B(tB2, 0, 0)); BAR();
        PHASE(0, 1, 4, false, STAGE_B(tB2, 1, 0)); VM4(); BAR();
        PHASE(1, 0, 0, true,  STAGE_A(tB2, 0, 0)); BAR();
        PHASE(1, 1, 0, true,  STAGE_A(tB2, 1, 0)); BAR();
        PHASE(1, 0, 4, false, STAGE_B(tB3, 0, 1)); BAR();
        PHASE(1, 1, 4, false, STAGE_B(tB3, 1, 1)); VM4(); BAR();
    }
    asm volatile("s_waitcnt vmcnt(0)" ::: "memory");   // drain all DMA (per-wave)
    BAR();                                              // everyone drained

    // ---- epilogue ----
    if constexpr (MODE == 0) {
        // gelu (tanh form, exp2-folded) -> bf16, swizzled LDS tile, coalesced store
        u16* lt = (u16*)smem;
#pragma unroll
        for (int m = 0; m < 8; ++m)
#pragma unroll
            for (int n = 0; n < 4; ++n) {
                const int lcol = wn * 64 + n * 16 + fr;
                const float bv = bias[ntile * 256 + lcol];
#pragma unroll
                for (int j = 0; j < 4; ++j) {
                    const int lrow = wm * 128 + m * 16 + fq * 4 + j;
                    float v = acc[m][n][j] + bv;
                    float z2 = -2.3021582f * (v + 0.044715f * v * v * v);
                    float g = v / (1.0f + exp2f(z2));
                    lt[lrow * 256 + (lcol ^ ((lrow & 7) << 3))] = f2b(g);
                }
            }
        asm volatile("s_waitcnt lgkmcnt(0)" ::: "memory");
        BAR();
        u16* hidp = (u16*)outp;
        const long gbase = (long)(mtile * 256) * H_ + ntile * 256;
#pragma unroll
        for (int it = 0; it < 16; ++it) {
            const unsigned off = (unsigned)it * 8192u + (unsigned)tid * 16u;
            const int lrow = off >> 9;
            const unsigned lcolb = off & 511u;
            short8 vv = *(const short8*)(smem + (unsigned)(lrow << 9) + (lcolb ^ ((unsigned)(lrow & 7) << 4)));
            *(short8*)((char*)hidp + (gbase + (long)lrow * H_) * 2 + lcolb) = vv;
        }
    } else {
        float* op = (float*)outp;
        const int ncnt = *cnt;
        const int orow0 = mtile * 256 + wm * 128;
        const int ocol0 = ntile * 256 + wn * 64;
#pragma unroll
        for (int m = 0; m < 8; ++m)
#pragma unroll
            for (int j = 0; j < 4; ++j) {
                const int row = orow0 + m * 16 + fq * 4 + j;
                if (row < ncnt) {
                    const long ob = (long)idx[row] * D_;
#pragma unroll
                    for (int n = 0; n < 4; ++n) {
                        const int col = ocol0 + n * 16 + fr;
                        op[ob + col] = acc[m][n][j] + bias[col];
                    }
                }
            }
    }
#undef PHASE
#undef STAGE_A
#undef STAGE_B
#undef BAR
#undef VM4
}

// ---------- launcher ----------
extern "C" void kernel_launch(void* const* d_in, const int* in_sizes, int n_in,
                              void* d_out, int out_size, void* d_ws, size_t ws_size,
                              hipStream_t stream) {
    const float* x   = (const float*)d_in[0];
    const float* w_r = (const float*)d_in[1];
    const float* b_r = (const float*)d_in[2];
    const float* W1  = (const float*)d_in[3];
    const float* b1  = (const float*)d_in[4];
    const float* W2  = (const float*)d_in[5];
    const float* b2  = (const float*)d_in[6];
    float* out = (float*)d_out;

    char* p = (char*)d_ws;
    auto alloc = [&](size_t bytes) {
        char* q = p;
        p += (bytes + 255) & ~(size_t)255;
        return q;
    };
    float* wts = (float*)alloc((size_t)NTOK * 4);
    float* thr = (float*)alloc(B_ * 4);
    int*   cnt = (int*)alloc(4);
    int*   idx = (int*)alloc((size_t)MPAD * 4);
    u16*   xb  = (u16*)alloc((size_t)NTOK * D_ * 2);
    u16*   w1t = (u16*)alloc((size_t)H_ * D_ * 2);
    u16*   w2t = (u16*)alloc((size_t)H_ * D_ * 2);
    u16*   hid = (u16*)alloc((size_t)MPAD * H_ * 2);

    auto k1 = gemm8p<16, 16, 0>;
    auto k2 = gemm8p<64, 4, 1>;
    (void)hipFuncSetAttribute((const void*)k1, hipFuncAttributeMaxDynamicSharedMemorySize, 131072);
    (void)hipFuncSetAttribute((const void*)k2, hipFuncAttributeMaxDynamicSharedMemorySize, 131072);

    init_kernel<<<MPAD / 256, 256, 0, stream>>>(idx, cnt);
    router_kernel<<<NTOK / 4, 256, 0, stream>>>(x, w_r, b_r, out, xb, wts);
    select_kernel<<<B_, 256, 0, stream>>>(wts, thr);
    compact_kernel<<<NTOK / 256, 256, 0, stream>>>(wts, thr, idx, cnt);
    transpose_kernel<<<dim3(H_ / 32, D_ / 32), 256, 0, stream>>>(W1, w1t, D_, H_);
    transpose_kernel<<<dim3(D_ / 32, H_ / 32), 256, 0, stream>>>(W2, w2t, H_, D_);
    k1<<<dim3(16, 64), 512, 131072, stream>>>(xb, w1t, b1, idx, nullptr, hid);
    k2<<<dim3(4, 64), 512, 131072, stream>>>(hid, w2t, b2, idx, cnt, out);
}